// Round 1
// 133.783 us; speedup vs baseline: 1.2160x; 1.2160x over previous
//
#include <hip/hip_runtime.h>

typedef unsigned short u16;
typedef __attribute__((ext_vector_type(8))) short bh8;
typedef __attribute__((ext_vector_type(4))) short s4;
typedef __attribute__((ext_vector_type(4))) short bh4;
typedef __attribute__((ext_vector_type(4))) float fx4;

__device__ __forceinline__ u16 f2b(float f) {
  union { float f; unsigned u; } v; v.f = f;
  unsigned r = v.u + 0x7fffu + ((v.u >> 16) & 1u);
  return (u16)(r >> 16);
}
__device__ __forceinline__ float b2f(u16 h) {
  union { unsigned u; float f; } v; v.u = ((unsigned)h) << 16; return v.f;
}

// fast 2^x
__device__ __forceinline__ float ex2(float x) {
#if __has_builtin(__builtin_amdgcn_exp2f)
  return __builtin_amdgcn_exp2f(x);
#else
  return __expf(x * 0.6931471805599453f);
#endif
}

// packed f32x2 -> bf16x2 (RNE, matches f2b)
__device__ __forceinline__ unsigned cvtpk(float lo, float hi) {
  unsigned r;
  asm("v_cvt_pk_bf16_f32 %0, %1, %2" : "=v"(r) : "v"(lo), "v"(hi));
  return r;
}

// 16x16x16 bf16 MFMA (K=16)
#if __has_builtin(__builtin_amdgcn_mfma_f32_16x16x16bf16_1k)
__device__ __forceinline__ fx4 pv_mfma(s4 a, s4 b, fx4 c) {
  return __builtin_amdgcn_mfma_f32_16x16x16bf16_1k(a, b, c, 0, 0, 0);
}
#else
__device__ __forceinline__ fx4 pv_mfma(s4 a, s4 b, fx4 c) {
  asm("v_mfma_f32_16x16x16_bf16 %0, %1, %2, %0" : "+v"(c) : "v"(a), "v"(b));
  return c;
}
#endif

// ---------- prep: X -> bf16 ----------
__global__ __launch_bounds__(256) void conv_x_k(const float* __restrict__ X, u16* __restrict__ Xb) {
  int i = blockIdx.x * 256 + threadIdx.x;
  float4 v = ((const float4*)X)[i];
  bh4 o; o[0]=(short)f2b(v.x); o[1]=(short)f2b(v.y); o[2]=(short)f2b(v.z); o[3]=(short)f2b(v.w);
  ((bh4*)Xb)[i] = o;
}

// ---------- prep: weights -> bf16, transposed to [N][K]; Wq scaled by dh^-0.5 * log2(e) ----------
__global__ __launch_bounds__(256) void conv_w_k(const float* __restrict__ Wq, const float* __restrict__ Wk,
                         const float* __restrict__ Wv, const float* __restrict__ Wo,
                         const float* __restrict__ W1, const float* __restrict__ W2,
                         u16* __restrict__ WqkvT, u16* __restrict__ WoT,
                         u16* __restrict__ W1T, u16* __restrict__ W2T) {
  int i = blockIdx.x * 256 + threadIdx.x;
  if (i < 196608) {                       // WqkvT [768][256]
    int n = i >> 8, k = i & 255; float v;
    if (n < 256) v = Wq[k*256+n] * 0.25503487359f;   // 1/sqrt(32) * log2(e)
    else if (n < 512) v = Wk[k*256+(n-256)];
    else v = Wv[k*256+(n-512)];
    WqkvT[i] = f2b(v);
  } else if (i < 262144) {                // WoT [256][256]
    int j = i - 196608; int n = j >> 8, k = j & 255;
    WoT[j] = f2b(Wo[k*256+n]);
  } else if (i < 393216) {                // W1T [512][256]
    int j = i - 262144; int n = j >> 8, k = j & 255;
    W1T[j] = f2b(W1[k*512+n]);
  } else {                                // W2T [256][512]
    int j = i - 393216; int n = j >> 9, k = j & 511;
    W2T[j] = f2b(W2[k*256+n]);
  }
}

// ---------- GEMM: C[M][N] = A[M][K] * BT[N][K]^T, bf16 in, fp32 acc ----------
// EPI 0: scatter q/k/v  1: plain bf16 store  2: +bias, relu  3: +bias
// XCD-aware tile remap (bijective, gridDim.y % 8 == 0) kept from prior round.
// NEW this round: LDS-staged coalesced epilogue. The 32KB staging LDS is dead
// after the K-loop; reuse it as a 128x128 u16 C tile (XOR-swizzled banks),
// then store 16B/lane fully-coalesced. vT blocks stage TRANSPOSED (n-major)
// so the old 2KB-stride u16 scatter becomes 256B-contiguous runs.
template<int K, int N, int EPI>
__global__ __launch_bounds__(256) void gemm_k(
    const u16* __restrict__ A, const u16* __restrict__ BT,
    u16* __restrict__ C0, u16* __restrict__ C1, u16* __restrict__ C2,
    const float* __restrict__ bias) {
  constexpr int BK = 32;
  __shared__ u16 smem[16384];            // [0:8192) = A dbuf, [8192:16384) = B dbuf; reused as C tile
  const int nx = gridDim.x;
  const int lid = blockIdx.y * nx + blockIdx.x;   // linear dispatch id (x fastest)
  const int xcd = lid & 7;
  const int jj2 = lid >> 3;
  const int m0 = (xcd * (gridDim.y >> 3) + jj2 / nx) * 128;
  const int n0 = (jj2 % nx) * 128;
  const int tid = threadIdx.x, lane = tid & 63, wv = tid >> 6;
  const int wr = wv >> 1, wc = wv & 1, lg = lane >> 4, ll = lane & 15;

  fx4 acc[4][4] = {};

  auto stage = [&](int buf, int ks) {
#pragma unroll
    for (int i = 0; i < 2; ++i) {
      int c = i*256 + tid;
      int row = c >> 2, ko = (c & 3) * 8;
      const u16* gpA = A  + (size_t)(m0+row)*K + ks + ko;
      const u16* gpB = BT + (size_t)(n0+row)*K + ks + ko;
      int lbase = (i*256 + wv*64) * 8;
      __builtin_amdgcn_global_load_lds((const __attribute__((address_space(1))) void*)gpA,
          (__attribute__((address_space(3))) void*)&smem[buf*4096 + lbase], 16, 0, 0);
      __builtin_amdgcn_global_load_lds((const __attribute__((address_space(1))) void*)gpB,
          (__attribute__((address_space(3))) void*)&smem[8192 + buf*4096 + lbase], 16, 0, 0);
    }
  };

  constexpr int NT = K / BK;
  stage(0, 0);
  __syncthreads();
  int cur = 0;
  for (int t = 0; t < NT; ++t) {
    if (t + 1 < NT) stage(cur ^ 1, (t+1)*BK);
    bh8 af[4], bfr[4];
#pragma unroll
    for (int mi = 0; mi < 4; ++mi)
      af[mi] = *(const bh8*)&smem[cur*4096 + (wr*64 + mi*16 + ll)*BK + lg*8];
#pragma unroll
    for (int ni = 0; ni < 4; ++ni)
      bfr[ni] = *(const bh8*)&smem[8192 + cur*4096 + (wc*64 + ni*16 + ll)*BK + lg*8];
#pragma unroll
    for (int mi = 0; mi < 4; ++mi)
#pragma unroll
      for (int ni = 0; ni < 4; ++ni)
        acc[mi][ni] = __builtin_amdgcn_mfma_f32_16x16x32_bf16(af[mi], bfr[ni], acc[mi][ni], 0, 0, 0);
    __syncthreads();                     // also guarantees LDS is dead after last iter
    cur ^= 1;
  }

  // ---- epilogue: acc -> LDS (swizzled) -> coalesced 16B stores ----
  // swz(r): XOR on col bits 4..6; multiples of 8 so 8-elem chunks stay contiguous.
  auto swz = [](int r) { return ((r & 14) << 2) ^ ((r & 3) << 5); };
  const bool vt = (EPI == 0) && (n0 >= 512);     // vT output blocks

  if (!vt) {
    float bv[4];
    if constexpr (EPI >= 2) {
#pragma unroll
      for (int ni = 0; ni < 4; ++ni) bv[ni] = bias[n0 + wc*64 + ni*16 + ll];
    }
#pragma unroll
    for (int mi = 0; mi < 4; ++mi)
#pragma unroll
      for (int ni = 0; ni < 4; ++ni) {
        fx4 v = acc[mi][ni];
        int n = wc*64 + ni*16 + ll;
#pragma unroll
        for (int ii = 0; ii < 2; ++ii) {
          float x0 = v[2*ii], x1 = v[2*ii+1];
          if constexpr (EPI == 2) { x0 = fmaxf(x0 + bv[ni], 0.f); x1 = fmaxf(x1 + bv[ni], 0.f); }
          else if constexpr (EPI == 3) { x0 += bv[ni]; x1 += bv[ni]; }
          unsigned pk = cvtpk(x0, x1);
          int mA = wr*64 + mi*16 + lg*4 + 2*ii;
          int mB = mA + 1;
          smem[mA*128 + (n ^ swz(mA))] = (u16)pk;
          smem[mB*128 + (n ^ swz(mB))] = (u16)(pk >> 16);
        }
      }
  } else {
    // transposed staging: LDS[n][m ^ swz(n)]; 4 m-consecutive acc elems pack to one b64 write
#pragma unroll
    for (int mi = 0; mi < 4; ++mi)
#pragma unroll
      for (int ni = 0; ni < 4; ++ni) {
        fx4 v = acc[mi][ni];
        int n = wc*64 + ni*16 + ll;
        int mb = wr*64 + mi*16 + lg*4;
        uint2 pk;
        pk.x = cvtpk(v[0], v[1]);
        pk.y = cvtpk(v[2], v[3]);
        *(uint2*)&smem[n*128 + (mb ^ swz(n))] = pk;
      }
  }
  __syncthreads();

  // read phase: 2048 chunks of 8 u16; 16 consecutive lanes cover one 256B LDS row
#pragma unroll
  for (int j = 0; j < 8; ++j) {
    int cid = tid + 256*j;
    int row = cid >> 4, c8 = (cid & 15) << 3;
    bh8 val = *(const bh8*)&smem[row*128 + (c8 ^ swz(row))];
    if constexpr (EPI == 0) {
      if (!vt) {                                   // q/k: [b][h][l][32], 8 contiguous d
        int m = m0 + row; int b = m >> 10, l = m & 1023;
        int n = n0 + c8; int hh = (n >> 5) & 7, d = n & 31;
        size_t bh_ = (size_t)(b*8 + hh);
        u16* dst = (n0 < 256) ? C0 : C1;
        *(bh8*)&dst[(bh_*1024 + l)*32 + d] = val;
      } else {                                     // vT: [b][h][32][1024], 8 contiguous l
        int n = n0 + row; int hh = (n >> 5) & 7, d = n & 31;
        int m = m0 + c8; int b = m >> 10, l = m & 1023;
        size_t bh_ = (size_t)(b*8 + hh);
        *(bh8*)&C2[(bh_*32 + d)*1024 + l] = val;
      }
    } else {
      *(bh8*)&C0[(size_t)(m0+row)*N + n0 + c8] = val;
    }
  }
}

// ---------- attention: one block per (qblock, head, batch); no LDS ----------
// Verbatim known-good kernel.
__global__ __launch_bounds__(256) void attn_k(
    const u16* __restrict__ qw, const u16* __restrict__ kw,
    const u16* __restrict__ vtw, u16* __restrict__ ao) {
  const int qb = blockIdx.x, hh = blockIdx.y, b = blockIdx.z;
  const int tid = threadIdx.x, lane = tid & 63, wv = tid >> 6;
  const int lg = lane >> 4, ll = lane & 15;
  const int kstart = qb ? (qb - 1) * 256 : 0;
  const size_t bh_ = (size_t)(b*8 + hh);
  const u16* kg = kw  + (bh_*1024 + kstart)*32;
  const u16* vg = vtw + bh_*32*1024 + kstart;
  const u16* qg = qw  + (bh_*1024 + qb*256)*32;

  bh8 qf[4];
#pragma unroll
  for (int qi = 0; qi < 4; ++qi)
    qf[qi] = *(const bh8*)&qg[(size_t)(wv*64 + qi*16 + ll)*32 + lg*8];

  fx4 oacc[4][2] = {};
  float lsum[4] = {0.f, 0.f, 0.f, 0.f};
  const fx4 zero = {0.f, 0.f, 0.f, 0.f};

  const int ch0 = wv*2;                          // ch for qi=0,1; qi=2,3 -> ch0+1
  const int lo_w = qb ? ch0 + 2 : 0;
  const int hi_w = qb ? ch0 + 9 : ch0 + 1;

  for (int ohm = lo_w; ohm <= hi_w; ++ohm) {
    const int kb = ohm * 32;
    bh8 kf0 = *(const bh8*)&kg[(size_t)(kb + ll)*32 + lg*8];
    bh8 kf1 = *(const bh8*)&kg[(size_t)(kb + 16 + ll)*32 + lg*8];
    s4 vb[2][2];
#pragma unroll
    for (int cs = 0; cs < 2; ++cs)
#pragma unroll
      for (int dsub = 0; dsub < 2; ++dsub)
        vb[cs][dsub] = *(const s4*)&vg[(size_t)(dsub*16 + ll)*1024 + kb + cs*16 + lg*4];

#pragma unroll
    for (int qi = 0; qi < 4; ++qi) {
      const int ch = ch0 + (qi >> 1);
      const int dlo = qb ? ch + 2 : 0;
      const int dhi = qb ? ch + 8 : ch;
      if (ohm < dlo || ohm > dhi) continue;                 // wave-uniform
      const bool diag = (ohm == dhi);

      fx4 s0 = __builtin_amdgcn_mfma_f32_16x16x32_bf16(kf0, qf[qi], zero, 0, 0, 0);
      fx4 s1 = __builtin_amdgcn_mfma_f32_16x16x32_bf16(kf1, qf[qi], zero, 0, 0, 0);
      // s{cs}[i] = S[key = kb + cs*16 + lg*4 + i][q = base+ll]

      const int cw = ll + ((qi & 1) << 4);                  // q % 32 for this lane
      float p[2][4];
      if (!qb && !diag) {
#pragma unroll
        for (int i = 0; i < 4; ++i) { p[0][i] = ex2(s0[i]); p[1][i] = ex2(s1[i]); }
      } else {
        const int off = (qb && !diag) ? 6 : 0;
        const unsigned thr = diag ? (qb ? 7u : 32u) : 13u;
#pragma unroll
        for (int cs = 0; cs < 2; ++cs) {
          const int tb = cw + off - cs*16 - lg*4;
          fx4 sv = cs ? s1 : s0;
#pragma unroll
          for (int i = 0; i < 4; ++i) {
            bool ok = (unsigned)(tb - i) < thr;             // ow = cs*16+lg*4+i
            p[cs][i] = ok ? ex2(sv[i]) : 0.f;
          }
        }
      }
      lsum[qi] += (p[0][0]+p[0][1]+p[0][2]+p[0][3]) + (p[1][0]+p[1][1]+p[1][2]+p[1][3]);

#pragma unroll
      for (int cs = 0; cs < 2; ++cs) {
        union { unsigned u[2]; s4 s; } cv;
        cv.u[0] = cvtpk(p[cs][0], p[cs][1]);
        cv.u[1] = cvtpk(p[cs][2], p[cs][3]);
#pragma unroll
        for (int dsub = 0; dsub < 2; ++dsub)
          oacc[qi][dsub] = pv_mfma(cv.s, vb[cs][dsub], oacc[qi][dsub]);
      }
    }
  }

  // row sums: lane (ll,lg) holds partials for q = base+ll; reduce over lg groups
  float rinv[4];
#pragma unroll
  for (int qi = 0; qi < 4; ++qi) {
    float v = lsum[qi];
    v += __shfl_xor(v, 16);
    v += __shfl_xor(v, 32);
    rinv[qi] = 1.0f / v;
  }

  u16* aop = ao + ((size_t)(b*1024 + qb*256))*256 + hh*32;
#pragma unroll
  for (int qi = 0; qi < 4; ++qi) {
    float rq[4];
#pragma unroll
    for (int i = 0; i < 4; ++i) rq[i] = __shfl(rinv[qi], lg*4 + i);
#pragma unroll
    for (int dsub = 0; dsub < 2; ++dsub)
#pragma unroll
      for (int i = 0; i < 4; ++i) {
        int q = wv*64 + qi*16 + lg*4 + i;                   // oacc row = q, col = d
        aop[(size_t)q*256 + dsub*16 + ll] = f2b(oacc[qi][dsub][i] * rq[i]);
      }
  }
}

// ---------- LayerNorm(y + xres) ----------
template<int XF32, int OF32>
__global__ __launch_bounds__(256) void ln_k(
    const u16* __restrict__ y, const void* __restrict__ xres,
    const float* __restrict__ g, const float* __restrict__ bb,
    void* __restrict__ out) {
  int row = blockIdx.x*4 + (threadIdx.x >> 6);
  int lane = threadIdx.x & 63;
  int c0 = lane * 4;
  size_t base = (size_t)row * 256 + c0;
  bh4 yv = *(const bh4*)&y[base];
  float s[4];
  if constexpr (XF32) {
    float4 xv = *(const float4*)&((const float*)xres)[base];
    s[0] = b2f((u16)yv[0]) + xv.x; s[1] = b2f((u16)yv[1]) + xv.y;
    s[2] = b2f((u16)yv[2]) + xv.z; s[3] = b2f((u16)yv[3]) + xv.w;
  } else {
    bh4 xv = *(const bh4*)&((const u16*)xres)[base];
#pragma unroll
    for (int j = 0; j < 4; ++j) s[j] = b2f((u16)yv[j]) + b2f((u16)xv[j]);
  }
  float sum = s[0]+s[1]+s[2]+s[3];
  float sq  = s[0]*s[0]+s[1]*s[1]+s[2]*s[2]+s[3]*s[3];
#pragma unroll
  for (int m = 1; m <= 32; m <<= 1) { sum += __shfl_xor(sum, m); sq += __shfl_xor(sq, m); }
  float mean = sum * 0.00390625f;
  float var  = sq  * 0.00390625f - mean*mean;
  float rs = rsqrtf(var + 1e-6f);
  float4 gv = *(const float4*)&g[c0];
  float4 bv = *(const float4*)&bb[c0];
  if constexpr (OF32) {
    float4 o;
    o.x = (s[0]-mean)*rs*gv.x + bv.x; o.y = (s[1]-mean)*rs*gv.y + bv.y;
    o.z = (s[2]-mean)*rs*gv.z + bv.z; o.w = (s[3]-mean)*rs*gv.w + bv.w;
    *(float4*)&((float*)out)[base] = o;
  } else {
    bh4 o;
    o[0] = (short)f2b((s[0]-mean)*rs*gv.x + bv.x);
    o[1] = (short)f2b((s[1]-mean)*rs*gv.y + bv.y);
    o[2] = (short)f2b((s[2]-mean)*rs*gv.z + bv.z);
    o[3] = (short)f2b((s[3]-mean)*rs*gv.w + bv.w);
    *(bh4*)&((u16*)out)[base] = o;
  }
}

extern "C" void kernel_launch(void* const* d_in, const int* in_sizes, int n_in,
                              void* d_out, int out_size, void* d_ws, size_t ws_size,
                              hipStream_t stream) {
  const float* X    = (const float*)d_in[0];
  const float* Wq   = (const float*)d_in[1];
  const float* Wk   = (const float*)d_in[2];
  const float* Wv   = (const float*)d_in[3];
  const float* Wo   = (const float*)d_in[4];
  const float* ln1g = (const float*)d_in[5];
  const float* ln1b = (const float*)d_in[6];
  const float* W1   = (const float*)d_in[7];
  const float* b1   = (const float*)d_in[8];
  const float* W2   = (const float*)d_in[9];
  const float* b2   = (const float*)d_in[10];
  const float* ln2g = (const float*)d_in[11];
  const float* ln2b = (const float*)d_in[12];
  float* out = (float*)d_out;

  char* ws = (char*)d_ws;
  const size_t A = 32768ull * 256 * 2;
  u16* Xb  = (u16*)(ws);
  u16* qws = (u16*)(ws + A);
  u16* kws = (u16*)(ws + 2*A);
  u16* vtw = (u16*)(ws + 3*A);
  u16* ao  = Xb;
  u16* yw  = qws;
  u16* x1b = kws;
  u16* y2  = vtw;
  u16* hw  = Xb;
  u16* WqkvT = (u16*)(ws + 4*A);
  u16* WoT = WqkvT + 196608;
  u16* W1T = WoT + 65536;
  u16* W2T = W1T + 131072;

  conv_x_k<<<8192, 256, 0, stream>>>(X, Xb);
  conv_w_k<<<2048, 256, 0, stream>>>(Wq, Wk, Wv, Wo, W1, W2, WqkvT, WoT, W1T, W2T);
  gemm_k<256, 768, 0><<<dim3(6, 256), 256, 0, stream>>>(Xb, WqkvT, qws, kws, vtw, nullptr);
  attn_k<<<dim3(4, 8, 32), 256, 0, stream>>>(qws, kws, vtw, ao);
  gemm_k<256, 256, 1><<<dim3(2, 256), 256, 0, stream>>>(ao, WoT, yw, nullptr, nullptr, nullptr);
  ln_k<1, 0><<<8192, 256, 0, stream>>>(yw, X, ln1g, ln1b, x1b);
  gemm_k<256, 512, 2><<<dim3(4, 256), 256, 0, stream>>>(x1b, W1T, hw, nullptr, nullptr, b1);
  gemm_k<512, 256, 3><<<dim3(2, 256), 256, 0, stream>>>(hw, W2T, y2, nullptr, nullptr, b2);
  ln_k<0, 1><<<8192, 256, 0, stream>>>(y2, x1b, ln2g, ln2b, out);
}

// Round 2
// 120.125 us; speedup vs baseline: 1.3543x; 1.1137x over previous
//
#include <hip/hip_runtime.h>

typedef unsigned short u16;
typedef __attribute__((ext_vector_type(8))) short bh8;
typedef __attribute__((ext_vector_type(4))) short s4;
typedef __attribute__((ext_vector_type(4))) short bh4;
typedef __attribute__((ext_vector_type(4))) float fx4;

__device__ __forceinline__ u16 f2b(float f) {
  union { float f; unsigned u; } v; v.f = f;
  unsigned r = v.u + 0x7fffu + ((v.u >> 16) & 1u);
  return (u16)(r >> 16);
}
__device__ __forceinline__ float b2f(u16 h) {
  union { unsigned u; float f; } v; v.u = ((unsigned)h) << 16; return v.f;
}

// fast 2^x
__device__ __forceinline__ float ex2(float x) {
#if __has_builtin(__builtin_amdgcn_exp2f)
  return __builtin_amdgcn_exp2f(x);
#else
  return __expf(x * 0.6931471805599453f);
#endif
}

// packed f32x2 -> bf16x2 (RNE, matches f2b)
__device__ __forceinline__ unsigned cvtpk(float lo, float hi) {
  unsigned r;
  asm("v_cvt_pk_bf16_f32 %0, %1, %2" : "=v"(r) : "v"(lo), "v"(hi));
  return r;
}

// 16x16x16 bf16 MFMA (K=16)
#if __has_builtin(__builtin_amdgcn_mfma_f32_16x16x16bf16_1k)
__device__ __forceinline__ fx4 pv_mfma(s4 a, s4 b, fx4 c) {
  return __builtin_amdgcn_mfma_f32_16x16x16bf16_1k(a, b, c, 0, 0, 0);
}
#else
__device__ __forceinline__ fx4 pv_mfma(s4 a, s4 b, fx4 c) {
  asm("v_mfma_f32_16x16x16_bf16 %0, %1, %2, %0" : "+v"(c) : "v"(a), "v"(b));
  return c;
}
#endif

// ---------- prep: weights -> bf16, transposed to [N][K]; Wq scaled by dh^-0.5 * log2(e) ----------
__global__ __launch_bounds__(256) void conv_w_k(const float* __restrict__ Wq, const float* __restrict__ Wk,
                         const float* __restrict__ Wv, const float* __restrict__ Wo,
                         const float* __restrict__ W1, const float* __restrict__ W2,
                         u16* __restrict__ WqkvT, u16* __restrict__ WoT,
                         u16* __restrict__ W1T, u16* __restrict__ W2T) {
  int i = blockIdx.x * 256 + threadIdx.x;
  if (i < 196608) {                       // WqkvT [768][256]
    int n = i >> 8, k = i & 255; float v;
    if (n < 256) v = Wq[k*256+n] * 0.25503487359f;   // 1/sqrt(32) * log2(e)
    else if (n < 512) v = Wk[k*256+(n-256)];
    else v = Wv[k*256+(n-512)];
    WqkvT[i] = f2b(v);
  } else if (i < 262144) {                // WoT [256][256]
    int j = i - 196608; int n = j >> 8, k = j & 255;
    WoT[j] = f2b(Wo[k*256+n]);
  } else if (i < 393216) {                // W1T [512][256]
    int j = i - 262144; int n = j >> 8, k = j & 255;
    W1T[j] = f2b(W1[k*512+n]);
  } else {                                // W2T [256][512]
    int j = i - 393216; int n = j >> 9, k = j & 511;
    W2T[j] = f2b(W2[k*256+n]);
  }
}

// ---------- GEMM: C[M][N] = A[M][K] * BT[N][K]^T, bf16 in, fp32 acc ----------
// EPI 0: scatter q/k/v  2: +bias, relu
// AF32: A is f32; staged via reg (global f32x4 -> cvt_pk -> ds_write_b64),
// issue-early / write-late so HBM latency hides under MFMA. Kills conv_x pass.
template<int K, int N, int EPI, int AF32>
__global__ __launch_bounds__(256) void gemm_k(
    const void* __restrict__ Av, const u16* __restrict__ BT,
    u16* __restrict__ C0, u16* __restrict__ C1, u16* __restrict__ C2,
    const float* __restrict__ bias) {
  constexpr int BK = 32;
  __shared__ u16 smem[16384];            // [0:8192) = A dbuf, [8192:16384) = B dbuf; reused as C tile
  const int nx = gridDim.x;
  const int lid = blockIdx.y * nx + blockIdx.x;
  const int xcd = lid & 7;
  const int jj2 = lid >> 3;
  const int m0 = (xcd * (gridDim.y >> 3) + jj2 / nx) * 128;
  const int n0 = (jj2 % nx) * 128;
  const int tid = threadIdx.x, lane = tid & 63, wv = tid >> 6;
  const int wr = wv >> 1, wc = wv & 1, lg = lane >> 4, ll = lane & 15;
  const u16* A16 = (const u16*)Av;
  const float* A32 = (const float*)Av;

  fx4 acc[4][4] = {};

  auto stageB = [&](int buf, int ks) {
#pragma unroll
    for (int i = 0; i < 2; ++i) {
      int c = i*256 + tid;
      int row = c >> 2, ko = (c & 3) * 8;
      const u16* gpB = BT + (size_t)(n0+row)*K + ks + ko;
      int lbase = (i*256 + wv*64) * 8;
      __builtin_amdgcn_global_load_lds((const __attribute__((address_space(1))) void*)gpB,
          (__attribute__((address_space(3))) void*)&smem[8192 + buf*4096 + lbase], 16, 0, 0);
    }
  };
  auto stageA16 = [&](int buf, int ks) {
#pragma unroll
    for (int i = 0; i < 2; ++i) {
      int c = i*256 + tid;
      int row = c >> 2, ko = (c & 3) * 8;
      const u16* gpA = A16 + (size_t)(m0+row)*K + ks + ko;
      int lbase = (i*256 + wv*64) * 8;
      __builtin_amdgcn_global_load_lds((const __attribute__((address_space(1))) void*)gpA,
          (__attribute__((address_space(3))) void*)&smem[buf*4096 + lbase], 16, 0, 0);
    }
  };
  float4 apf[4];
  auto loadA32 = [&](int ks) {
#pragma unroll
    for (int i = 0; i < 4; ++i) {
      int c = i*256 + tid;
      int row = c >> 3, c4 = (c & 7) * 4;
      apf[i] = *(const float4*)&A32[(size_t)(m0+row)*K + ks + c4];
    }
  };
  auto writeA32 = [&](int buf) {
#pragma unroll
    for (int i = 0; i < 4; ++i) {
      int c = i*256 + tid;
      int row = c >> 3, c4 = (c & 7) * 4;
      uint2 pk;
      pk.x = cvtpk(apf[i].x, apf[i].y);
      pk.y = cvtpk(apf[i].z, apf[i].w);
      *(uint2*)&smem[buf*4096 + row*32 + c4] = pk;
    }
  };

  constexpr int NT = K / BK;
  if constexpr (AF32) { loadA32(0); writeA32(0); } else stageA16(0, 0);
  stageB(0, 0);
  __syncthreads();
  int cur = 0;
  for (int t = 0; t < NT; ++t) {
    if (t + 1 < NT) {
      if constexpr (AF32) loadA32((t+1)*BK); else stageA16(cur ^ 1, (t+1)*BK);
      stageB(cur ^ 1, (t+1)*BK);
    }
    bh8 af[4], bfr[4];
#pragma unroll
    for (int mi = 0; mi < 4; ++mi)
      af[mi] = *(const bh8*)&smem[cur*4096 + (wr*64 + mi*16 + ll)*BK + lg*8];
#pragma unroll
    for (int ni = 0; ni < 4; ++ni)
      bfr[ni] = *(const bh8*)&smem[8192 + cur*4096 + (wc*64 + ni*16 + ll)*BK + lg*8];
#pragma unroll
    for (int mi = 0; mi < 4; ++mi)
#pragma unroll
      for (int ni = 0; ni < 4; ++ni)
        acc[mi][ni] = __builtin_amdgcn_mfma_f32_16x16x32_bf16(af[mi], bfr[ni], acc[mi][ni], 0, 0, 0);
    if constexpr (AF32) { if (t + 1 < NT) writeA32(cur ^ 1); }
    __syncthreads();
    cur ^= 1;
  }

  // ---- epilogue: acc -> LDS (swizzled) -> coalesced 16B stores ----
  auto swz = [](int r) { return ((r & 14) << 2) ^ ((r & 3) << 5); };
  const bool vt = (EPI == 0) && (n0 >= 512);     // vT output blocks

  if (!vt) {
    float bv[4];
    if constexpr (EPI >= 2) {
#pragma unroll
      for (int ni = 0; ni < 4; ++ni) bv[ni] = bias[n0 + wc*64 + ni*16 + ll];
    }
#pragma unroll
    for (int mi = 0; mi < 4; ++mi)
#pragma unroll
      for (int ni = 0; ni < 4; ++ni) {
        fx4 v = acc[mi][ni];
        int n = wc*64 + ni*16 + ll;
#pragma unroll
        for (int ii = 0; ii < 2; ++ii) {
          float x0 = v[2*ii], x1 = v[2*ii+1];
          if constexpr (EPI == 2) { x0 = fmaxf(x0 + bv[ni], 0.f); x1 = fmaxf(x1 + bv[ni], 0.f); }
          unsigned pk = cvtpk(x0, x1);
          int mA = wr*64 + mi*16 + lg*4 + 2*ii;
          int mB = mA + 1;
          smem[mA*128 + (n ^ swz(mA))] = (u16)pk;
          smem[mB*128 + (n ^ swz(mB))] = (u16)(pk >> 16);
        }
      }
  } else {
    // transposed staging: LDS[n][m ^ swz(n)]
#pragma unroll
    for (int mi = 0; mi < 4; ++mi)
#pragma unroll
      for (int ni = 0; ni < 4; ++ni) {
        fx4 v = acc[mi][ni];
        int n = wc*64 + ni*16 + ll;
        int mb = wr*64 + mi*16 + lg*4;
        uint2 pk;
        pk.x = cvtpk(v[0], v[1]);
        pk.y = cvtpk(v[2], v[3]);
        *(uint2*)&smem[n*128 + (mb ^ swz(n))] = pk;
      }
  }
  __syncthreads();

#pragma unroll
  for (int j = 0; j < 8; ++j) {
    int cid = tid + 256*j;
    int row = cid >> 4, c8 = (cid & 15) << 3;
    bh8 val = *(const bh8*)&smem[row*128 + (c8 ^ swz(row))];
    if constexpr (EPI == 0) {
      if (!vt) {                                   // q/k: [b][h][l][32]
        int m = m0 + row; int b = m >> 10, l = m & 1023;
        int n = n0 + c8; int hh = (n >> 5) & 7, d = n & 31;
        size_t bh_ = (size_t)(b*8 + hh);
        u16* dst = (n0 < 256) ? C0 : C1;
        *(bh8*)&dst[(bh_*1024 + l)*32 + d] = val;
      } else {                                     // vT: [b][h][32][1024]
        int n = n0 + row; int hh = (n >> 5) & 7, d = n & 31;
        int m = m0 + c8; int b = m >> 10, l = m & 1023;
        size_t bh_ = (size_t)(b*8 + hh);
        *(bh8*)&C2[(bh_*32 + d)*1024 + l] = val;
      }
    } else {
      *(bh8*)&C0[(size_t)(m0+row)*N + n0 + c8] = val;
    }
  }
}

// ---------- fused GEMM + residual + LayerNorm ----------
// C = A[M][K] * BT[256][K]^T (+bias); out = LN(C + resid) row-wise.
// Tile 64x256 (full N per block -> row-local LN). 4 waves, each 32x128,
// acc[2][8]. MFMA operands SWAPPED vs gemm_k so the 4 acc elems per reg are
// n-consecutive -> pack to one ds_write_b64 into the [64][256] u16 C tile
// (XOR-swizzled 8B granules). Then per-wave row loop: LDS row + resid ->
// shfl-reduce mean/var -> scale -> store.
template<int K, int RF32, int OF32, int BIAS>
__global__ __launch_bounds__(256) void gemm_ln_k(
    const u16* __restrict__ A, const u16* __restrict__ BT,
    const void* __restrict__ resid, const float* __restrict__ bias,
    const float* __restrict__ g, const float* __restrict__ b,
    void* __restrict__ out) {
  constexpr int BK = 32;
  __shared__ u16 smem[20480];   // A dbuf [2][2048) @0, B dbuf [2][8192) @4096; C tile [64][256] @0
  const int lid = blockIdx.y;
  const int xcd = lid & 7;
  const int jj2 = lid >> 3;
  const int m0 = (xcd * (gridDim.y >> 3) + jj2) * 64;
  const int tid = threadIdx.x, lane = tid & 63, wv = tid >> 6;
  const int wr = wv >> 1, wc = wv & 1, lg = lane >> 4, ll = lane & 15;

  fx4 acc[2][8] = {};

  auto stage = [&](int buf, int ks) {
    {
      int c = tid;
      int row = c >> 2, ko = (c & 3) * 8;
      const u16* gpA = A + (size_t)(m0+row)*K + ks + ko;
      int lbase = wv*512;
      __builtin_amdgcn_global_load_lds((const __attribute__((address_space(1))) void*)gpA,
          (__attribute__((address_space(3))) void*)&smem[buf*2048 + lbase], 16, 0, 0);
    }
#pragma unroll
    for (int i = 0; i < 4; ++i) {
      int c = i*256 + tid;
      int row = c >> 2, ko = (c & 3) * 8;
      const u16* gpB = BT + (size_t)row*K + ks + ko;
      int lbase = (i*256 + wv*64) * 8;
      __builtin_amdgcn_global_load_lds((const __attribute__((address_space(1))) void*)gpB,
          (__attribute__((address_space(3))) void*)&smem[4096 + buf*8192 + lbase], 16, 0, 0);
    }
  };

  constexpr int NT = K / BK;
  stage(0, 0);
  __syncthreads();
  int cur = 0;
  for (int t = 0; t < NT; ++t) {
    if (t + 1 < NT) stage(cur ^ 1, (t+1)*BK);
    bh8 af[2], bfr[8];
#pragma unroll
    for (int mi = 0; mi < 2; ++mi)
      af[mi] = *(const bh8*)&smem[cur*2048 + (wr*32 + mi*16 + ll)*BK + lg*8];
#pragma unroll
    for (int ni = 0; ni < 8; ++ni)
      bfr[ni] = *(const bh8*)&smem[4096 + cur*8192 + (wc*128 + ni*16 + ll)*BK + lg*8];
#pragma unroll
    for (int mi = 0; mi < 2; ++mi)
#pragma unroll
      for (int ni = 0; ni < 8; ++ni)
        acc[mi][ni] = __builtin_amdgcn_mfma_f32_16x16x32_bf16(bfr[ni], af[mi], acc[mi][ni], 0, 0, 0);
    __syncthreads();
    cur ^= 1;
  }

  // stage C tile: row m_l = wr*32+mi*16+ll, cols n_l..n_l+3 = wc*128+ni*16+lg*4
#pragma unroll
  for (int mi = 0; mi < 2; ++mi) {
    int m_l = wr*32 + mi*16 + ll;
    int sx = (m_l & 7) << 1;
#pragma unroll
    for (int ni = 0; ni < 8; ++ni) {
      fx4 v = acc[mi][ni];
      int gidx = (wc*32 + ni*4 + lg) ^ sx;
      uint2 pk;
      pk.x = cvtpk(v[0], v[1]);
      pk.y = cvtpk(v[2], v[3]);
      *(uint2*)&smem[m_l*256 + gidx*4] = pk;
    }
  }
  __syncthreads();

  // per-row LN: wave wv handles rows wv*16 .. wv*16+15; lane covers cols lane*4..+3
  const int c0 = lane * 4;
  float4 gv = *(const float4*)&g[c0];
  float4 bv = *(const float4*)&b[c0];
  float4 biasv = {0.f, 0.f, 0.f, 0.f};
  if constexpr (BIAS) biasv = *(const float4*)&bias[c0];
#pragma unroll 4
  for (int rr = 0; rr < 16; ++rr) {
    int r = wv*16 + rr;
    bh4 yv = *(const bh4*)&smem[r*256 + ((lane ^ ((r & 7) << 1)) << 2)];
    size_t gbase = (size_t)(m0 + r) * 256 + c0;
    float s0, s1, s2, s3;
    if constexpr (RF32) {
      float4 xv = *(const float4*)&((const float*)resid)[gbase];
      s0 = b2f((u16)yv[0]) + biasv.x + xv.x;
      s1 = b2f((u16)yv[1]) + biasv.y + xv.y;
      s2 = b2f((u16)yv[2]) + biasv.z + xv.z;
      s3 = b2f((u16)yv[3]) + biasv.w + xv.w;
    } else {
      bh4 xv = *(const bh4*)&((const u16*)resid)[gbase];
      s0 = b2f((u16)yv[0]) + biasv.x + b2f((u16)xv[0]);
      s1 = b2f((u16)yv[1]) + biasv.y + b2f((u16)xv[1]);
      s2 = b2f((u16)yv[2]) + biasv.z + b2f((u16)xv[2]);
      s3 = b2f((u16)yv[3]) + biasv.w + b2f((u16)xv[3]);
    }
    float sum = s0 + s1 + s2 + s3;
    float sq  = s0*s0 + s1*s1 + s2*s2 + s3*s3;
#pragma unroll
    for (int msk = 1; msk <= 32; msk <<= 1) {
      sum += __shfl_xor(sum, msk);
      sq  += __shfl_xor(sq, msk);
    }
    float mean = sum * 0.00390625f;
    float var  = sq  * 0.00390625f - mean*mean;
    float rs = rsqrtf(var + 1e-6f);
    float o0 = (s0 - mean)*rs*gv.x + bv.x;
    float o1 = (s1 - mean)*rs*gv.y + bv.y;
    float o2 = (s2 - mean)*rs*gv.z + bv.z;
    float o3 = (s3 - mean)*rs*gv.w + bv.w;
    if constexpr (OF32) {
      float4 o = {o0, o1, o2, o3};
      *(float4*)&((float*)out)[gbase] = o;
    } else {
      bh4 o;
      o[0] = (short)f2b(o0); o[1] = (short)f2b(o1);
      o[2] = (short)f2b(o2); o[3] = (short)f2b(o3);
      *(bh4*)&((u16*)out)[gbase] = o;
    }
  }
}

// ---------- attention: one block per (qblock, head, batch); no LDS ----------
// Verbatim known-good kernel.
__global__ __launch_bounds__(256) void attn_k(
    const u16* __restrict__ qw, const u16* __restrict__ kw,
    const u16* __restrict__ vtw, u16* __restrict__ ao) {
  const int qb = blockIdx.x, hh = blockIdx.y, b = blockIdx.z;
  const int tid = threadIdx.x, lane = tid & 63, wv = tid >> 6;
  const int lg = lane >> 4, ll = lane & 15;
  const int kstart = qb ? (qb - 1) * 256 : 0;
  const size_t bh_ = (size_t)(b*8 + hh);
  const u16* kg = kw  + (bh_*1024 + kstart)*32;
  const u16* vg = vtw + bh_*32*1024 + kstart;
  const u16* qg = qw  + (bh_*1024 + qb*256)*32;

  bh8 qf[4];
#pragma unroll
  for (int qi = 0; qi < 4; ++qi)
    qf[qi] = *(const bh8*)&qg[(size_t)(wv*64 + qi*16 + ll)*32 + lg*8];

  fx4 oacc[4][2] = {};
  float lsum[4] = {0.f, 0.f, 0.f, 0.f};
  const fx4 zero = {0.f, 0.f, 0.f, 0.f};

  const int ch0 = wv*2;
  const int lo_w = qb ? ch0 + 2 : 0;
  const int hi_w = qb ? ch0 + 9 : ch0 + 1;

  for (int ohm = lo_w; ohm <= hi_w; ++ohm) {
    const int kb = ohm * 32;
    bh8 kf0 = *(const bh8*)&kg[(size_t)(kb + ll)*32 + lg*8];
    bh8 kf1 = *(const bh8*)&kg[(size_t)(kb + 16 + ll)*32 + lg*8];
    s4 vb[2][2];
#pragma unroll
    for (int cs = 0; cs < 2; ++cs)
#pragma unroll
      for (int dsub = 0; dsub < 2; ++dsub)
        vb[cs][dsub] = *(const s4*)&vg[(size_t)(dsub*16 + ll)*1024 + kb + cs*16 + lg*4];

#pragma unroll
    for (int qi = 0; qi < 4; ++qi) {
      const int ch = ch0 + (qi >> 1);
      const int dlo = qb ? ch + 2 : 0;
      const int dhi = qb ? ch + 8 : ch;
      if (ohm < dlo || ohm > dhi) continue;                 // wave-uniform
      const bool diag = (ohm == dhi);

      fx4 s0 = __builtin_amdgcn_mfma_f32_16x16x32_bf16(kf0, qf[qi], zero, 0, 0, 0);
      fx4 s1 = __builtin_amdgcn_mfma_f32_16x16x32_bf16(kf1, qf[qi], zero, 0, 0, 0);

      const int cw = ll + ((qi & 1) << 4);
      float p[2][4];
      if (!qb && !diag) {
#pragma unroll
        for (int i = 0; i < 4; ++i) { p[0][i] = ex2(s0[i]); p[1][i] = ex2(s1[i]); }
      } else {
        const int off = (qb && !diag) ? 6 : 0;
        const unsigned thr = diag ? (qb ? 7u : 32u) : 13u;
#pragma unroll
        for (int cs = 0; cs < 2; ++cs) {
          const int tb = cw + off - cs*16 - lg*4;
          fx4 sv = cs ? s1 : s0;
#pragma unroll
          for (int i = 0; i < 4; ++i) {
            bool ok = (unsigned)(tb - i) < thr;
            p[cs][i] = ok ? ex2(sv[i]) : 0.f;
          }
        }
      }
      lsum[qi] += (p[0][0]+p[0][1]+p[0][2]+p[0][3]) + (p[1][0]+p[1][1]+p[1][2]+p[1][3]);

#pragma unroll
      for (int cs = 0; cs < 2; ++cs) {
        union { unsigned u[2]; s4 s; } cv;
        cv.u[0] = cvtpk(p[cs][0], p[cs][1]);
        cv.u[1] = cvtpk(p[cs][2], p[cs][3]);
#pragma unroll
        for (int dsub = 0; dsub < 2; ++dsub)
          oacc[qi][dsub] = pv_mfma(cv.s, vb[cs][dsub], oacc[qi][dsub]);
      }
    }
  }

  float rinv[4];
#pragma unroll
  for (int qi = 0; qi < 4; ++qi) {
    float v = lsum[qi];
    v += __shfl_xor(v, 16);
    v += __shfl_xor(v, 32);
    rinv[qi] = 1.0f / v;
  }

  u16* aop = ao + ((size_t)(b*1024 + qb*256))*256 + hh*32;
#pragma unroll
  for (int qi = 0; qi < 4; ++qi) {
    float rq[4];
#pragma unroll
    for (int i = 0; i < 4; ++i) rq[i] = __shfl(rinv[qi], lg*4 + i);
#pragma unroll
    for (int dsub = 0; dsub < 2; ++dsub)
#pragma unroll
      for (int i = 0; i < 4; ++i) {
        int q = wv*64 + qi*16 + lg*4 + i;
        aop[(size_t)q*256 + dsub*16 + ll] = f2b(oacc[qi][dsub][i] * rq[i]);
      }
  }
}

extern "C" void kernel_launch(void* const* d_in, const int* in_sizes, int n_in,
                              void* d_out, int out_size, void* d_ws, size_t ws_size,
                              hipStream_t stream) {
  const float* X    = (const float*)d_in[0];
  const float* Wq   = (const float*)d_in[1];
  const float* Wk   = (const float*)d_in[2];
  const float* Wv   = (const float*)d_in[3];
  const float* Wo   = (const float*)d_in[4];
  const float* ln1g = (const float*)d_in[5];
  const float* ln1b = (const float*)d_in[6];
  const float* W1   = (const float*)d_in[7];
  const float* b1   = (const float*)d_in[8];
  const float* W2   = (const float*)d_in[9];
  const float* b2   = (const float*)d_in[10];
  const float* ln2g = (const float*)d_in[11];
  const float* ln2b = (const float*)d_in[12];
  float* out = (float*)d_out;

  char* ws = (char*)d_ws;
  const size_t A = 32768ull * 256 * 2;
  u16* qws = (u16*)(ws + A);
  u16* kws = (u16*)(ws + 2*A);
  u16* vtw = (u16*)(ws + 3*A);
  u16* ao  = (u16*)(ws);          // attn out [b][l][h*32] = [32768][256]
  u16* x1b = kws;                 // LN1 out bf16
  u16* hw  = (u16*)(ws);          // relu hidden [32768][512]
  u16* WqkvT = (u16*)(ws + 4*A);
  u16* WoT = WqkvT + 196608;
  u16* W1T = WoT + 65536;
  u16* W2T = W1T + 131072;

  conv_w_k<<<2048, 256, 0, stream>>>(Wq, Wk, Wv, Wo, W1, W2, WqkvT, WoT, W1T, W2T);
  gemm_k<256, 768, 0, 1><<<dim3(6, 256), 256, 0, stream>>>(X, WqkvT, qws, kws, vtw, nullptr);
  attn_k<<<dim3(4, 8, 32), 256, 0, stream>>>(qws, kws, vtw, ao);
  gemm_ln_k<256, 1, 0, 0><<<dim3(1, 512), 256, 0, stream>>>(ao, WoT, X, nullptr, ln1g, ln1b, x1b);
  gemm_k<256, 512, 2, 0><<<dim3(4, 256), 256, 0, stream>>>(x1b, W1T, hw, nullptr, nullptr, b1);
  gemm_ln_k<512, 0, 1, 1><<<dim3(1, 512), 256, 0, stream>>>(hw, W2T, x1b, b2, ln2g, ln2b, out);
}

// Round 3
// 119.599 us; speedup vs baseline: 1.3602x; 1.0044x over previous
//
#include <hip/hip_runtime.h>

typedef unsigned short u16;
typedef __attribute__((ext_vector_type(8))) short bh8;
typedef __attribute__((ext_vector_type(4))) short s4;
typedef __attribute__((ext_vector_type(4))) short bh4;
typedef __attribute__((ext_vector_type(4))) float fx4;

__device__ __forceinline__ u16 f2b(float f) {
  union { float f; unsigned u; } v; v.f = f;
  unsigned r = v.u + 0x7fffu + ((v.u >> 16) & 1u);
  return (u16)(r >> 16);
}
__device__ __forceinline__ float b2f(u16 h) {
  union { unsigned u; float f; } v; v.u = ((unsigned)h) << 16; return v.f;
}

// fast 2^x
__device__ __forceinline__ float ex2(float x) {
#if __has_builtin(__builtin_amdgcn_exp2f)
  return __builtin_amdgcn_exp2f(x);
#else
  return __expf(x * 0.6931471805599453f);
#endif
}

// packed f32x2 -> bf16x2 (RNE, matches f2b)
__device__ __forceinline__ unsigned cvtpk(float lo, float hi) {
  unsigned r;
  asm("v_cvt_pk_bf16_f32 %0, %1, %2" : "=v"(r) : "v"(lo), "v"(hi));
  return r;
}

// 16x16x16 bf16 MFMA (K=16)
#if __has_builtin(__builtin_amdgcn_mfma_f32_16x16x16bf16_1k)
__device__ __forceinline__ fx4 pv_mfma(s4 a, s4 b, fx4 c) {
  return __builtin_amdgcn_mfma_f32_16x16x16bf16_1k(a, b, c, 0, 0, 0);
}
#else
__device__ __forceinline__ fx4 pv_mfma(s4 a, s4 b, fx4 c) {
  asm("v_mfma_f32_16x16x16_bf16 %0, %1, %2, %0" : "+v"(c) : "v"(a), "v"(b));
  return c;
}
#endif

// ---------- prep: weights -> bf16, transposed to [N][K]; Wq scaled by dh^-0.5 * log2(e) ----------
__global__ __launch_bounds__(256) void conv_w_k(const float* __restrict__ Wq, const float* __restrict__ Wk,
                         const float* __restrict__ Wv, const float* __restrict__ Wo,
                         const float* __restrict__ W1, const float* __restrict__ W2,
                         u16* __restrict__ WqkvT, u16* __restrict__ WoT,
                         u16* __restrict__ W1T, u16* __restrict__ W2T) {
  int i = blockIdx.x * 256 + threadIdx.x;
  if (i < 196608) {                       // WqkvT [768][256]
    int n = i >> 8, k = i & 255; float v;
    if (n < 256) v = Wq[k*256+n] * 0.25503487359f;   // 1/sqrt(32) * log2(e)
    else if (n < 512) v = Wk[k*256+(n-256)];
    else v = Wv[k*256+(n-512)];
    WqkvT[i] = f2b(v);
  } else if (i < 262144) {                // WoT [256][256]
    int j = i - 196608; int n = j >> 8, k = j & 255;
    WoT[j] = f2b(Wo[k*256+n]);
  } else if (i < 393216) {                // W1T [512][256]
    int j = i - 262144; int n = j >> 8, k = j & 255;
    W1T[j] = f2b(W1[k*512+n]);
  } else {                                // W2T [256][512]
    int j = i - 393216; int n = j >> 9, k = j & 511;
    W2T[j] = f2b(W2[k*256+n]);
  }
}

// ---------- GEMM: C[M][N] = A[M][K] * BT[N][K]^T, bf16 in, fp32 acc ----------
// EPI 0: scatter q/k/v  2: +bias, relu
// AF32=1: A is f32, staged RAW via global_load_lds (no reg round-trip, no
// per-iter drain chain); f32->bf16 conversion at LDS-read time via cvt_pk.
// A source addresses are XOR-pre-swizzled (po ^= (row&7)<<4 within each 128B
// row, rule #21) so the stride-128B ds_read_b128 pattern is conflict-free.
template<int K, int N, int EPI, int AF32>
__global__ __launch_bounds__(256) void gemm_k(
    const void* __restrict__ Av, const u16* __restrict__ BT,
    u16* __restrict__ C0, u16* __restrict__ C1, u16* __restrict__ C2,
    const float* __restrict__ bias) {
  constexpr int BK = 32;
  // u16 units: AF32: A f32 dbuf [0,16384) (2x16KB), B [16384,24576) (2x8KB) = 48KB
  //            else: A [0,8192) (2x8KB),            B [8192,16384)  (2x8KB) = 32KB
  __shared__ u16 smem[AF32 ? 24576 : 16384];
  constexpr int ABUF = AF32 ? 8192 : 4096;   // per-buf A stride (u16)
  constexpr int BOFF = AF32 ? 16384 : 8192;  // B region base (u16)
  const int nx = gridDim.x;
  const int lid = blockIdx.y * nx + blockIdx.x;
  const int xcd = lid & 7;
  const int jj2 = lid >> 3;
  const int m0 = (xcd * (gridDim.y >> 3) + jj2 / nx) * 128;
  const int n0 = (jj2 % nx) * 128;
  const int tid = threadIdx.x, lane = tid & 63, wv = tid >> 6;
  const int wr = wv >> 1, wc = wv & 1, lg = lane >> 4, ll = lane & 15;
  const u16* A16 = (const u16*)Av;
  const float* A32 = (const float*)Av;

  fx4 acc[4][4] = {};

  auto stageB = [&](int buf, int ks) {
#pragma unroll
    for (int i = 0; i < 2; ++i) {
      int c = i*256 + tid;
      int row = c >> 2, ko = (c & 3) * 8;
      const u16* gpB = BT + (size_t)(n0+row)*K + ks + ko;
      int lbase = BOFF + buf*4096 + (i*256 + wv*64) * 8;
      __builtin_amdgcn_global_load_lds((const __attribute__((address_space(1))) void*)gpB,
          (__attribute__((address_space(3))) void*)&smem[lbase], 16, 0, 0);
    }
  };
  auto stageA16 = [&](int buf, int ks) {
#pragma unroll
    for (int i = 0; i < 2; ++i) {
      int c = i*256 + tid;
      int row = c >> 2, ko = (c & 3) * 8;
      const u16* gpA = A16 + (size_t)(m0+row)*K + ks + ko;
      int lbase = buf*ABUF + (i*256 + wv*64) * 8;
      __builtin_amdgcn_global_load_lds((const __attribute__((address_space(1))) void*)gpA,
          (__attribute__((address_space(3))) void*)&smem[lbase], 16, 0, 0);
    }
  };
  // A f32 tile: 128 rows x 32 f32 (128B/row) = 16KB = 1024 16B chunks, 4/thread.
  // LDS linear; global source pre-swizzled: logical byte = physical ^ ((row&7)<<4).
  auto stageA32 = [&](int buf, int ks) {
#pragma unroll
    for (int i = 0; i < 4; ++i) {
      int c = i*256 + tid;
      int r = c >> 3;
      int po = (c & 7) * 16;                 // physical byte offset within row
      int lo = po ^ ((r & 7) << 4);          // logical (source) byte offset
      const float* gpA = A32 + (size_t)(m0 + r)*K + ks + (lo >> 2);
      int lbase = buf*ABUF + (i*256 + wv*64) * 8;     // u16 idx; chunk = 16B
      __builtin_amdgcn_global_load_lds((const __attribute__((address_space(1))) void*)gpA,
          (__attribute__((address_space(3))) void*)&smem[lbase], 16, 0, 0);
    }
  };

  constexpr int NT = K / BK;
  if constexpr (AF32) stageA32(0, 0); else stageA16(0, 0);
  stageB(0, 0);
  __syncthreads();
  int cur = 0;
  for (int t = 0; t < NT; ++t) {
    if (t + 1 < NT) {
      if constexpr (AF32) stageA32(cur ^ 1, (t+1)*BK); else stageA16(cur ^ 1, (t+1)*BK);
      stageB(cur ^ 1, (t+1)*BK);
    }
    bh8 af[4], bfr[4];
    if constexpr (AF32) {
#pragma unroll
      for (int mi = 0; mi < 4; ++mi) {
        int r = wr*64 + mi*16 + ll;
        int sw = (r & 7) << 4;
        int b0 = r*128 + ((lg*32) ^ sw);
        int b1 = r*128 + ((lg*32 + 16) ^ sw);
        float4 a0 = *(const float4*)&smem[cur*ABUF + (b0 >> 1)];
        float4 a1 = *(const float4*)&smem[cur*ABUF + (b1 >> 1)];
        union { unsigned u[4]; bh8 v; } cvt;
        cvt.u[0] = cvtpk(a0.x, a0.y); cvt.u[1] = cvtpk(a0.z, a0.w);
        cvt.u[2] = cvtpk(a1.x, a1.y); cvt.u[3] = cvtpk(a1.z, a1.w);
        af[mi] = cvt.v;
      }
    } else {
#pragma unroll
      for (int mi = 0; mi < 4; ++mi)
        af[mi] = *(const bh8*)&smem[cur*ABUF + (wr*64 + mi*16 + ll)*BK + lg*8];
    }
#pragma unroll
    for (int ni = 0; ni < 4; ++ni)
      bfr[ni] = *(const bh8*)&smem[BOFF + cur*4096 + (wc*64 + ni*16 + ll)*BK + lg*8];
#pragma unroll
    for (int mi = 0; mi < 4; ++mi)
#pragma unroll
      for (int ni = 0; ni < 4; ++ni)
        acc[mi][ni] = __builtin_amdgcn_mfma_f32_16x16x32_bf16(af[mi], bfr[ni], acc[mi][ni], 0, 0, 0);
    __syncthreads();
    cur ^= 1;
  }

  // ---- epilogue: acc -> LDS (swizzled) -> coalesced 16B stores ----
  auto swz = [](int r) { return ((r & 14) << 2) ^ ((r & 3) << 5); };
  const bool vt = (EPI == 0) && (n0 >= 512);     // vT output blocks

  if (!vt) {
    float bv[4];
    if constexpr (EPI >= 2) {
#pragma unroll
      for (int ni = 0; ni < 4; ++ni) bv[ni] = bias[n0 + wc*64 + ni*16 + ll];
    }
#pragma unroll
    for (int mi = 0; mi < 4; ++mi)
#pragma unroll
      for (int ni = 0; ni < 4; ++ni) {
        fx4 v = acc[mi][ni];
        int n = wc*64 + ni*16 + ll;
#pragma unroll
        for (int ii = 0; ii < 2; ++ii) {
          float x0 = v[2*ii], x1 = v[2*ii+1];
          if constexpr (EPI == 2) { x0 = fmaxf(x0 + bv[ni], 0.f); x1 = fmaxf(x1 + bv[ni], 0.f); }
          unsigned pk = cvtpk(x0, x1);
          int mA = wr*64 + mi*16 + lg*4 + 2*ii;
          int mB = mA + 1;
          smem[mA*128 + (n ^ swz(mA))] = (u16)pk;
          smem[mB*128 + (n ^ swz(mB))] = (u16)(pk >> 16);
        }
      }
  } else {
    // transposed staging: LDS[n][m ^ swz(n)]
#pragma unroll
    for (int mi = 0; mi < 4; ++mi)
#pragma unroll
      for (int ni = 0; ni < 4; ++ni) {
        fx4 v = acc[mi][ni];
        int n = wc*64 + ni*16 + ll;
        int mb = wr*64 + mi*16 + lg*4;
        uint2 pk;
        pk.x = cvtpk(v[0], v[1]);
        pk.y = cvtpk(v[2], v[3]);
        *(uint2*)&smem[n*128 + (mb ^ swz(n))] = pk;
      }
  }
  __syncthreads();

#pragma unroll
  for (int j = 0; j < 8; ++j) {
    int cid = tid + 256*j;
    int row = cid >> 4, c8 = (cid & 15) << 3;
    bh8 val = *(const bh8*)&smem[row*128 + (c8 ^ swz(row))];
    if constexpr (EPI == 0) {
      if (!vt) {                                   // q/k: [b][h][l][32]
        int m = m0 + row; int b = m >> 10, l = m & 1023;
        int n = n0 + c8; int hh = (n >> 5) & 7, d = n & 31;
        size_t bh_ = (size_t)(b*8 + hh);
        u16* dst = (n0 < 256) ? C0 : C1;
        *(bh8*)&dst[(bh_*1024 + l)*32 + d] = val;
      } else {                                     // vT: [b][h][32][1024]
        int n = n0 + row; int hh = (n >> 5) & 7, d = n & 31;
        int m = m0 + c8; int b = m >> 10, l = m & 1023;
        size_t bh_ = (size_t)(b*8 + hh);
        *(bh8*)&C2[(bh_*32 + d)*1024 + l] = val;
      }
    } else {
      *(bh8*)&C0[(size_t)(m0+row)*N + n0 + c8] = val;
    }
  }
}

// ---------- fused GEMM + residual + LayerNorm ----------
// C = A[M][K] * BT[256][K]^T (+bias); out = LN(C + resid) row-wise.
// Tile 64x256 (full N per block -> row-local LN). MFMA operands swapped so
// acc elems are n-consecutive -> ds_write_b64 into [64][256] u16 C tile.
template<int K, int RF32, int OF32, int BIAS>
__global__ __launch_bounds__(256) void gemm_ln_k(
    const u16* __restrict__ A, const u16* __restrict__ BT,
    const void* __restrict__ resid, const float* __restrict__ bias,
    const float* __restrict__ g, const float* __restrict__ b,
    void* __restrict__ out) {
  constexpr int BK = 32;
  __shared__ u16 smem[20480];   // A dbuf [2][2048) @0, B dbuf [2][8192) @4096; C tile [64][256] @0
  const int lid = blockIdx.y;
  const int xcd = lid & 7;
  const int jj2 = lid >> 3;
  const int m0 = (xcd * (gridDim.y >> 3) + jj2) * 64;
  const int tid = threadIdx.x, lane = tid & 63, wv = tid >> 6;
  const int wr = wv >> 1, wc = wv & 1, lg = lane >> 4, ll = lane & 15;

  fx4 acc[2][8] = {};

  auto stage = [&](int buf, int ks) {
    {
      int c = tid;
      int row = c >> 2, ko = (c & 3) * 8;
      const u16* gpA = A + (size_t)(m0+row)*K + ks + ko;
      int lbase = wv*512;
      __builtin_amdgcn_global_load_lds((const __attribute__((address_space(1))) void*)gpA,
          (__attribute__((address_space(3))) void*)&smem[buf*2048 + lbase], 16, 0, 0);
    }
#pragma unroll
    for (int i = 0; i < 4; ++i) {
      int c = i*256 + tid;
      int row = c >> 2, ko = (c & 3) * 8;
      const u16* gpB = BT + (size_t)row*K + ks + ko;
      int lbase = (i*256 + wv*64) * 8;
      __builtin_amdgcn_global_load_lds((const __attribute__((address_space(1))) void*)gpB,
          (__attribute__((address_space(3))) void*)&smem[4096 + buf*8192 + lbase], 16, 0, 0);
    }
  };

  constexpr int NT = K / BK;
  stage(0, 0);
  __syncthreads();
  int cur = 0;
  for (int t = 0; t < NT; ++t) {
    if (t + 1 < NT) stage(cur ^ 1, (t+1)*BK);
    bh8 af[2], bfr[8];
#pragma unroll
    for (int mi = 0; mi < 2; ++mi)
      af[mi] = *(const bh8*)&smem[cur*2048 + (wr*32 + mi*16 + ll)*BK + lg*8];
#pragma unroll
    for (int ni = 0; ni < 8; ++ni)
      bfr[ni] = *(const bh8*)&smem[4096 + cur*8192 + (wc*128 + ni*16 + ll)*BK + lg*8];
#pragma unroll
    for (int mi = 0; mi < 2; ++mi)
#pragma unroll
      for (int ni = 0; ni < 8; ++ni)
        acc[mi][ni] = __builtin_amdgcn_mfma_f32_16x16x32_bf16(bfr[ni], af[mi], acc[mi][ni], 0, 0, 0);
    __syncthreads();
    cur ^= 1;
  }

  // stage C tile: row m_l = wr*32+mi*16+ll, cols n_l..n_l+3 = wc*128+ni*16+lg*4
#pragma unroll
  for (int mi = 0; mi < 2; ++mi) {
    int m_l = wr*32 + mi*16 + ll;
    int sx = (m_l & 7) << 1;
#pragma unroll
    for (int ni = 0; ni < 8; ++ni) {
      fx4 v = acc[mi][ni];
      int gidx = (wc*32 + ni*4 + lg) ^ sx;
      uint2 pk;
      pk.x = cvtpk(v[0], v[1]);
      pk.y = cvtpk(v[2], v[3]);
      *(uint2*)&smem[m_l*256 + gidx*4] = pk;
    }
  }
  __syncthreads();

  // per-row LN: wave wv handles rows wv*16 .. wv*16+15; lane covers cols lane*4..+3
  const int c0 = lane * 4;
  float4 gv = *(const float4*)&g[c0];
  float4 bv = *(const float4*)&b[c0];
  float4 biasv = {0.f, 0.f, 0.f, 0.f};
  if constexpr (BIAS) biasv = *(const float4*)&bias[c0];
#pragma unroll 4
  for (int rr = 0; rr < 16; ++rr) {
    int r = wv*16 + rr;
    bh4 yv = *(const bh4*)&smem[r*256 + ((lane ^ ((r & 7) << 1)) << 2)];
    size_t gbase = (size_t)(m0 + r) * 256 + c0;
    float s0, s1, s2, s3;
    if constexpr (RF32) {
      float4 xv = *(const float4*)&((const float*)resid)[gbase];
      s0 = b2f((u16)yv[0]) + biasv.x + xv.x;
      s1 = b2f((u16)yv[1]) + biasv.y + xv.y;
      s2 = b2f((u16)yv[2]) + biasv.z + xv.z;
      s3 = b2f((u16)yv[3]) + biasv.w + xv.w;
    } else {
      bh4 xv = *(const bh4*)&((const u16*)resid)[gbase];
      s0 = b2f((u16)yv[0]) + biasv.x + b2f((u16)xv[0]);
      s1 = b2f((u16)yv[1]) + biasv.y + b2f((u16)xv[1]);
      s2 = b2f((u16)yv[2]) + biasv.z + b2f((u16)xv[2]);
      s3 = b2f((u16)yv[3]) + biasv.w + b2f((u16)xv[3]);
    }
    float sum = s0 + s1 + s2 + s3;
    float sq  = s0*s0 + s1*s1 + s2*s2 + s3*s3;
#pragma unroll
    for (int msk = 1; msk <= 32; msk <<= 1) {
      sum += __shfl_xor(sum, msk);
      sq  += __shfl_xor(sq, msk);
    }
    float mean = sum * 0.00390625f;
    float var  = sq  * 0.00390625f - mean*mean;
    float rs = rsqrtf(var + 1e-6f);
    float o0 = (s0 - mean)*rs*gv.x + bv.x;
    float o1 = (s1 - mean)*rs*gv.y + bv.y;
    float o2 = (s2 - mean)*rs*gv.z + bv.z;
    float o3 = (s3 - mean)*rs*gv.w + bv.w;
    if constexpr (OF32) {
      float4 o = {o0, o1, o2, o3};
      *(float4*)&((float*)out)[gbase] = o;
    } else {
      bh4 o;
      o[0] = (short)f2b(o0); o[1] = (short)f2b(o1);
      o[2] = (short)f2b(o2); o[3] = (short)f2b(o3);
      *(bh4*)&((u16*)out)[gbase] = o;
    }
  }
}

// ---------- attention: one block per (qblock, head, batch); no LDS ----------
// Verbatim known-good kernel.
__global__ __launch_bounds__(256) void attn_k(
    const u16* __restrict__ qw, const u16* __restrict__ kw,
    const u16* __restrict__ vtw, u16* __restrict__ ao) {
  const int qb = blockIdx.x, hh = blockIdx.y, b = blockIdx.z;
  const int tid = threadIdx.x, lane = tid & 63, wv = tid >> 6;
  const int lg = lane >> 4, ll = lane & 15;
  const int kstart = qb ? (qb - 1) * 256 : 0;
  const size_t bh_ = (size_t)(b*8 + hh);
  const u16* kg = kw  + (bh_*1024 + kstart)*32;
  const u16* vg = vtw + bh_*32*1024 + kstart;
  const u16* qg = qw  + (bh_*1024 + qb*256)*32;

  bh8 qf[4];
#pragma unroll
  for (int qi = 0; qi < 4; ++qi)
    qf[qi] = *(const bh8*)&qg[(size_t)(wv*64 + qi*16 + ll)*32 + lg*8];

  fx4 oacc[4][2] = {};
  float lsum[4] = {0.f, 0.f, 0.f, 0.f};
  const fx4 zero = {0.f, 0.f, 0.f, 0.f};

  const int ch0 = wv*2;
  const int lo_w = qb ? ch0 + 2 : 0;
  const int hi_w = qb ? ch0 + 9 : ch0 + 1;

  for (int ohm = lo_w; ohm <= hi_w; ++ohm) {
    const int kb = ohm * 32;
    bh8 kf0 = *(const bh8*)&kg[(size_t)(kb + ll)*32 + lg*8];
    bh8 kf1 = *(const bh8*)&kg[(size_t)(kb + 16 + ll)*32 + lg*8];
    s4 vb[2][2];
#pragma unroll
    for (int cs = 0; cs < 2; ++cs)
#pragma unroll
      for (int dsub = 0; dsub < 2; ++dsub)
        vb[cs][dsub] = *(const s4*)&vg[(size_t)(dsub*16 + ll)*1024 + kb + cs*16 + lg*4];

#pragma unroll
    for (int qi = 0; qi < 4; ++qi) {
      const int ch = ch0 + (qi >> 1);
      const int dlo = qb ? ch + 2 : 0;
      const int dhi = qb ? ch + 8 : ch;
      if (ohm < dlo || ohm > dhi) continue;                 // wave-uniform
      const bool diag = (ohm == dhi);

      fx4 s0 = __builtin_amdgcn_mfma_f32_16x16x32_bf16(kf0, qf[qi], zero, 0, 0, 0);
      fx4 s1 = __builtin_amdgcn_mfma_f32_16x16x32_bf16(kf1, qf[qi], zero, 0, 0, 0);

      const int cw = ll + ((qi & 1) << 4);
      float p[2][4];
      if (!qb && !diag) {
#pragma unroll
        for (int i = 0; i < 4; ++i) { p[0][i] = ex2(s0[i]); p[1][i] = ex2(s1[i]); }
      } else {
        const int off = (qb && !diag) ? 6 : 0;
        const unsigned thr = diag ? (qb ? 7u : 32u) : 13u;
#pragma unroll
        for (int cs = 0; cs < 2; ++cs) {
          const int tb = cw + off - cs*16 - lg*4;
          fx4 sv = cs ? s1 : s0;
#pragma unroll
          for (int i = 0; i < 4; ++i) {
            bool ok = (unsigned)(tb - i) < thr;
            p[cs][i] = ok ? ex2(sv[i]) : 0.f;
          }
        }
      }
      lsum[qi] += (p[0][0]+p[0][1]+p[0][2]+p[0][3]) + (p[1][0]+p[1][1]+p[1][2]+p[1][3]);

#pragma unroll
      for (int cs = 0; cs < 2; ++cs) {
        union { unsigned u[2]; s4 s; } cv;
        cv.u[0] = cvtpk(p[cs][0], p[cs][1]);
        cv.u[1] = cvtpk(p[cs][2], p[cs][3]);
#pragma unroll
        for (int dsub = 0; dsub < 2; ++dsub)
          oacc[qi][dsub] = pv_mfma(cv.s, vb[cs][dsub], oacc[qi][dsub]);
      }
    }
  }

  float rinv[4];
#pragma unroll
  for (int qi = 0; qi < 4; ++qi) {
    float v = lsum[qi];
    v += __shfl_xor(v, 16);
    v += __shfl_xor(v, 32);
    rinv[qi] = 1.0f / v;
  }

  u16* aop = ao + ((size_t)(b*1024 + qb*256))*256 + hh*32;
#pragma unroll
  for (int qi = 0; qi < 4; ++qi) {
    float rq[4];
#pragma unroll
    for (int i = 0; i < 4; ++i) rq[i] = __shfl(rinv[qi], lg*4 + i);
#pragma unroll
    for (int dsub = 0; dsub < 2; ++dsub)
#pragma unroll
      for (int i = 0; i < 4; ++i) {
        int q = wv*64 + qi*16 + lg*4 + i;
        aop[(size_t)q*256 + dsub*16 + ll] = f2b(oacc[qi][dsub][i] * rq[i]);
      }
  }
}

extern "C" void kernel_launch(void* const* d_in, const int* in_sizes, int n_in,
                              void* d_out, int out_size, void* d_ws, size_t ws_size,
                              hipStream_t stream) {
  const float* X    = (const float*)d_in[0];
  const float* Wq   = (const float*)d_in[1];
  const float* Wk   = (const float*)d_in[2];
  const float* Wv   = (const float*)d_in[3];
  const float* Wo   = (const float*)d_in[4];
  const float* ln1g = (const float*)d_in[5];
  const float* ln1b = (const float*)d_in[6];
  const float* W1   = (const float*)d_in[7];
  const float* b1   = (const float*)d_in[8];
  const float* W2   = (const float*)d_in[9];
  const float* b2   = (const float*)d_in[10];
  const float* ln2g = (const float*)d_in[11];
  const float* ln2b = (const float*)d_in[12];
  float* out = (float*)d_out;

  char* ws = (char*)d_ws;
  const size_t A = 32768ull * 256 * 2;
  u16* qws = (u16*)(ws + A);
  u16* kws = (u16*)(ws + 2*A);
  u16* vtw = (u16*)(ws + 3*A);
  u16* ao  = (u16*)(ws);          // attn out [b][l][h*32] = [32768][256]
  u16* x1b = kws;                 // LN1 out bf16
  u16* hw  = (u16*)(ws);          // relu hidden [32768][512]
  u16* WqkvT = (u16*)(ws + 4*A);
  u16* WoT = WqkvT + 196608;
  u16* W1T = WoT + 65536;
  u16* W2T = W1T + 131072;

  conv_w_k<<<2048, 256, 0, stream>>>(Wq, Wk, Wv, Wo, W1, W2, WqkvT, WoT, W1T, W2T);
  gemm_k<256, 768, 0, 1><<<dim3(6, 256), 256, 0, stream>>>(X, WqkvT, qws, kws, vtw, nullptr);
  attn_k<<<dim3(4, 8, 32), 256, 0, stream>>>(qws, kws, vtw, ao);
  gemm_ln_k<256, 1, 0, 0><<<dim3(1, 512), 256, 0, stream>>>(ao, WoT, X, nullptr, ln1g, ln1b, x1b);
  gemm_k<256, 512, 2, 0><<<dim3(4, 256), 256, 0, stream>>>(x1b, W1T, hw, nullptr, nullptr, b1);
  gemm_ln_k<512, 0, 1, 1><<<dim3(1, 512), 256, 0, stream>>>(hw, W2T, x1b, b2, ln2g, ln2b, out);
}